// Round 9
// baseline (175.464 us; speedup 1.0000x reference)
//
#include <hip/hip_runtime.h>

typedef __attribute__((ext_vector_type(8))) short bf16x8;
typedef __attribute__((ext_vector_type(4))) float f32x4;
typedef unsigned int u32;
typedef unsigned short u16;
typedef unsigned long long u64;

#define S0 384
#define PLANE0 (384 * 384)
#define XR 386                     // packed image dim (386x386 records)
#define XROWB ((size_t)XR * 256)   // 98816 B per packed row

__device__ __forceinline__ u16 bfr(float f) {   // f32 -> bf16 RNE
    u32 b = __float_as_uint(f);
    b += 0x7fff + ((b >> 16) & 1);
    return (u16)(b >> 16);
}

// ---------------------------------------------------------------------------
// Fused: blocks 0..127 = weight-compose prep (E, beff); blocks 128..322 = v.
// ---------------------------------------------------------------------------
__global__ __launch_bounds__(256) void k_prep_v(
        const float* __restrict__ cw, const float* __restrict__ cb,
        u16* __restrict__ Ebf2, float* __restrict__ beff,
        const float* __restrict__ V,
        const float* __restrict__ lin0_w, const float* __restrict__ lin0_b,
        float* __restrict__ v_out) {
    const int tid = threadIdx.x;
    if (blockIdx.x < 128) {
        // ---- prep E: E[o,tap,ic] = sum_m W[o,m,a,b] W[m,ic,c,d], tap=(a+c,b+d)
        int o = blockIdx.x, i = tid & 127;    // upper half duplicates (benign)
        __shared__ float4 Wo[128];
        __shared__ float red[128];
        Wo[i] = *(const float4*)(cw + (size_t)(o * 128 + i) * 4);
        __syncthreads();
        float a9[9];
#pragma unroll
        for (int q = 0; q < 9; ++q) a9[q] = 0.f;
        for (int m = 0; m < 128; ++m) {
            float4 w1 = *(const float4*)(cw + (size_t)(m * 128 + i) * 4);  // W[m][i]
            float4 w2 = Wo[m];                                             // W[o][m]
            a9[0] += w2.x * w1.x;
            a9[1] += w2.x * w1.y + w2.y * w1.x;
            a9[2] += w2.y * w1.y;
            a9[3] += w2.x * w1.z + w2.z * w1.x;
            a9[4] += w2.x * w1.w + w2.y * w1.z + w2.z * w1.y + w2.w * w1.x;
            a9[5] += w2.y * w1.w + w2.w * w1.y;
            a9[6] += w2.z * w1.z;
            a9[7] += w2.z * w1.w + w2.w * w1.z;
            a9[8] += w2.w * w1.w;
        }
        int icg = i >> 5, el = i & 31;
#pragma unroll
        for (int q = 0; q < 9; ++q)
            Ebf2[(size_t)((q * 4 + icg) * 128 + o) * 32 + el] = bfr(a9[q]);
        float4 wo = Wo[i];
        red[i] = cb[i] * (wo.x + wo.y + wo.z + wo.w);
        __syncthreads();
        for (int s = 64; s > 0; s >>= 1) {
            if (tid < 128 && i < s) red[i] += red[i + s];
            __syncthreads();
        }
        if (tid == 0) beff[o] = cb[o] + red[0];
    } else {
        // ---- v stage
        int blk = blockIdx.x - 128;        // 0..194
        int k = blk / 65, m = blk % 65;
        int d = tid;                        // 0..255
        int t = d >> 5, f = d & 31;
        const float* vbase = V + (size_t)t * 384 * 33 + f;
        float acc = lin0_b[m];
        for (int r = 0; r < 128; ++r) {
            float w = lin0_w[m * 130 + r];
            acc += w * vbase[(3 * r + k) * 33];
        }
        v_out[(size_t)blk * 256 + d] = acc;
    }
}

// ---------------------------------------------------------------------------
// Stage 2: attention scalars A[k,t] (9 floats)
// ---------------------------------------------------------------------------
__global__ void k_att(const float* __restrict__ v,
                      const float* __restrict__ att_w,
                      const float* __restrict__ att_b,
                      const float* __restrict__ agg,
                      float* __restrict__ A_out) {
    int k = blockIdx.x;
    int tid = threadIdx.x;
    __shared__ float wv1[256], wv2[256];
    __shared__ float sbuf[3][65];
    __shared__ float Ck_s;
    __shared__ float sm[3];
    {
        int d = tid;
        float a1 = 0.f, a2 = 0.f;
        for (int h = 0; h < 64; ++h) {
            float w = att_w[((size_t)(k * 64 + h)) * 256 + d];
            a1 += agg[k * 128 + h] * w;
            a2 += agg[k * 128 + 64 + h] * w;
        }
        wv1[d] = a1;
        wv2[d] = a2;
    }
    if (tid == 0) {
        float c = 0.f;
        for (int h = 0; h < 64; ++h)
            c += (agg[k * 128 + h] + agg[k * 128 + 64 + h]) * att_b[k * 64 + h];
        Ck_s = c;
    }
    __syncthreads();
    if (tid < 195) {
        int t = tid / 65, m = tid % 65;
        const float* vt = v + ((size_t)(t * 65 + m)) * 256;
        const float* vk = v + ((size_t)(k * 65 + m)) * 256;
        float s = Ck_s;
        for (int d = 0; d < 256; ++d)
            s += vt[d] * wv1[d] + vk[d] * wv2[d];
        s = s > 0.f ? s : 0.01f * s;
        sbuf[t][m] = s;
    }
    __syncthreads();
    if (tid < 3) {
        float mx = sbuf[tid][0];
        for (int m = 1; m < 65; ++m) mx = fmaxf(mx, sbuf[tid][m]);
        sm[tid] = mx;
    }
    __syncthreads();
    if (tid == 0) {
        float mx = fmaxf(sm[0], fmaxf(sm[1], sm[2]));
        float e0 = __expf(sm[0] - mx), e1 = __expf(sm[1] - mx), e2 = __expf(sm[2] - mx);
        float inv = 1.f / (e0 + e1 + e2);
        A_out[k * 3 + 0] = e0 * inv;
        A_out[k * 3 + 1] = e1 * inv;
        A_out[k * 3 + 2] = e2 * inv;
    }
}

// ---------------------------------------------------------------------------
// Pack (coalesced transpose) + border zeroing fused.
// X[y][x][slot j 16B]: slot j holds ic-octet (j ^ (x&15)) of
// graph[.][y][x] * att9[y%3][x%3], bf16; zero outside 384x384.
// grid (3, 386), 256 threads.
// ---------------------------------------------------------------------------
__global__ __launch_bounds__(256) void k_pack(
        const float* __restrict__ graph,
        const float* __restrict__ A9g,
        u16* __restrict__ X) {
    __shared__ u16 T[128 * 136];
    const int tid = threadIdx.x;
    const int xt = blockIdx.x, y = blockIdx.y;
    const int x0p = xt * 128;
    const uint4 z = {0u, 0u, 0u, 0u};

    if (y >= 384) {   // rows 384,385: all-zero
        int nunits = (xt == 2) ? 130 * 16 : 128 * 16;
        for (int u = tid; u < nunits; u += 256) {
            int x = x0p + (u >> 4), j = u & 15;
            *(uint4*)((char*)X + ((size_t)y * XR + x) * 256 + j * 16) = z;
        }
        return;
    }

    // phase A: read 4 ic x 16 x, transpose into LDS
    const int ic0 = (tid & 31) * 4;
    const int xc = tid >> 5;                 // 0..7
    float ar[3];
    ar[0] = A9g[(y % 3) * 3 + 0];
    ar[1] = A9g[(y % 3) * 3 + 1];
    ar[2] = A9g[(y % 3) * 3 + 2];
    const int m0 = (x0p + xc * 16) % 3;
    float facs[3];
    facs[0] = ar[m0];
    facs[1] = ar[m0 + 1 == 3 ? 0 : m0 + 1];
    facs[2] = ar[m0 + 2 >= 3 ? m0 - 1 : m0 + 2];

    float vals[4][16];
#pragma unroll
    for (int ici = 0; ici < 4; ++ici) {
        const float* g = graph + (size_t)(ic0 + ici) * PLANE0 + (size_t)y * S0 + x0p + xc * 16;
#pragma unroll
        for (int q = 0; q < 4; ++q) {
            float4 f = *(const float4*)(g + q * 4);
            vals[ici][q * 4 + 0] = f.x;
            vals[ici][q * 4 + 1] = f.y;
            vals[ici][q * 4 + 2] = f.z;
            vals[ici][q * 4 + 3] = f.w;
        }
    }
#pragma unroll
    for (int e = 0; e < 16; ++e) {
        float f = facs[e % 3];
        int x = xc * 16 + e;
        u16 q0 = bfr(vals[0][e] * f);
        u16 q1 = bfr(vals[1][e] * f);
        u16 q2 = bfr(vals[2][e] * f);
        u16 q3 = bfr(vals[3][e] * f);
        u64 w = (u64)q0 | ((u64)q1 << 16) | ((u64)q2 << 32) | ((u64)q3 << 48);
        *(u64*)(T + x * 136 + ic0) = w;
    }
    __syncthreads();

    // phase B: apply swizzle, write coalesced 16B units
#pragma unroll
    for (int i = 0; i < 8; ++i) {
        int u = tid + 256 * i;               // 0..2047
        int x = u >> 4, j = u & 15;
        int oct = j ^ (x & 15);
        uint4 w = *(const uint4*)(T + x * 136 + oct * 8);
        *(uint4*)((char*)X + ((size_t)y * XR + x0p + x) * 256 + j * 16) = w;
    }
    // cols 384,385 zero (only xt==2 borders them)
    if (xt == 2 && tid < 32) {
        int x = 384 + (tid >> 4), j = tid & 15;
        *(uint4*)((char*)X + ((size_t)y * XR + x) * 256 + j * 16) = z;
    }
}

// ---------------------------------------------------------------------------
// Fused 3x3 conv (composed 2x2∘2x2), GEMM M=128oc K=1152 N=147456px.
// PURE STREAMING: no LDS, no barriers.  B-fragments read DIRECTLY from the
// packed X (fragment-layout-exact; a wave's 64 lanes consume 16 full 64B
// lines -> coalesced).  A and B in depth-2 register pipelines; 16 MFMA/step.
// Block: 128oc x 64px x 2rows (N=128); wave = 64oc (mh) x 64px x 1row (rh).
// Epilogue: out = relu(pl*(acc+beff)+graph).
// grid 1152 = 8 XCD x 144 (chunked swizzle), 256 threads, 3 waves/EU.
// ---------------------------------------------------------------------------
__global__ __launch_bounds__(256, 3) void k_conv9(
        const u16* __restrict__ X,
        const short* __restrict__ Ebf2,
        const float* __restrict__ beff,
        const float* __restrict__ pl,
        const float* __restrict__ graph,
        float* __restrict__ out) {
    const int tid = threadIdx.x;
    const int lane = tid & 63, wave = tid >> 6;
    const int l15 = lane & 15, l16 = lane >> 4;

    const int phys = blockIdx.x;                // 0..1151 = 8 x 144
    const int logical = (phys & 7) * 144 + (phys >> 3);
    const int bx = logical % 6, by = logical / 6;
    const int x0 = bx * 64, y0 = by * 2;
    const int mh = wave & 1, rh = wave >> 1;
    const int ocbase = mh * 64;

    const char* Xbase = (const char*)X + ((size_t)(y0 + rh) * XR + x0) * 256;

    // A fragment loads (Ebf2 is L2-hot: 295 KB shared by all blocks)
#define ALOAD(dst, s) {                                                        \
        const short* Ap = Ebf2 + ((size_t)((s) * 128 + ocbase + l15) << 5)     \
                          + l16 * 8;                                           \
        dst[0] = *(const bf16x8*)(Ap);                                         \
        dst[1] = *(const bf16x8*)(Ap + 512);                                   \
        dst[2] = *(const bf16x8*)(Ap + 1024);                                  \
        dst[3] = *(const bf16x8*)(Ap + 1536); }

    // B fragment global offset for k-step s, N-frag n (s,n compile-time)
#define BOFF(s, n) ((size_t)(((s) >> 2) / 3) * XROWB                           \
        + ((l15 + (n) * 16 + ((s) >> 2) % 3) << 8)                             \
        + (((((s) & 3) * 4 + l16) ^ ((l15 + (n) * 16 + ((s) >> 2) % 3) & 15)) << 4))

#define BLOAD(dst, s) {                                                        \
        dst[0] = *(const bf16x8*)(Xbase + BOFF(s, 0));                         \
        dst[1] = *(const bf16x8*)(Xbase + BOFF(s, 1));                         \
        dst[2] = *(const bf16x8*)(Xbase + BOFF(s, 2));                         \
        dst[3] = *(const bf16x8*)(Xbase + BOFF(s, 3)); }

    bf16x8 ap[2][4], bp[2][4];
    ALOAD(ap[0], 0); BLOAD(bp[0], 0);
    ALOAD(ap[1], 1); BLOAD(bp[1], 1);

    f32x4 acc[4][4];    // [m][n]
#pragma unroll
    for (int a = 0; a < 4; ++a)
#pragma unroll
        for (int b = 0; b < 4; ++b)
            acc[a][b] = (f32x4){0.f, 0.f, 0.f, 0.f};

#pragma unroll
    for (int s = 0; s < 36; ++s) {
        const int cur = s & 1;
        __builtin_amdgcn_s_setprio(1);
#pragma unroll
        for (int n = 0; n < 4; ++n) {
            acc[0][n] = __builtin_amdgcn_mfma_f32_16x16x32_bf16(ap[cur][0], bp[cur][n], acc[0][n], 0, 0, 0);
            acc[1][n] = __builtin_amdgcn_mfma_f32_16x16x32_bf16(ap[cur][1], bp[cur][n], acc[1][n], 0, 0, 0);
            acc[2][n] = __builtin_amdgcn_mfma_f32_16x16x32_bf16(ap[cur][2], bp[cur][n], acc[2][n], 0, 0, 0);
            acc[3][n] = __builtin_amdgcn_mfma_f32_16x16x32_bf16(ap[cur][3], bp[cur][n], acc[3][n], 0, 0, 0);
        }
        __builtin_amdgcn_s_setprio(0);
        if (s + 2 < 36) { ALOAD(ap[cur], s + 2); BLOAD(bp[cur], s + 2); }
    }
#undef ALOAD
#undef BLOAD
#undef BOFF

    // ---- epilogue: out = relu(pl*(acc + beff) + graph) ----
    const float plv = pl[0];
    const int yy = y0 + rh;
#pragma unroll
    for (int m = 0; m < 4; ++m) {
#pragma unroll
        for (int r4 = 0; r4 < 4; ++r4) {
            const int oc = ocbase + m * 16 + l16 * 4 + r4;
            const float bias = beff[oc];
            const float* grow = graph + (size_t)oc * PLANE0 + (size_t)yy * S0 + x0;
            float* orow = out + (size_t)oc * PLANE0 + (size_t)yy * S0 + x0;
#pragma unroll
            for (int n = 0; n < 4; ++n) {
                const int xx = n * 16 + l15;
                float v = plv * (acc[m][n][r4] + bias) + grow[xx];
                orow[xx] = v > 0.f ? v : 0.f;
            }
        }
    }
}

// ---------------------------------------------------------------------------
extern "C" void kernel_launch(void* const* d_in, const int* in_sizes, int n_in,
                              void* d_out, int out_size, void* d_ws, size_t ws_size,
                              hipStream_t stream) {
    (void)in_sizes; (void)n_in; (void)out_size; (void)ws_size;
    const float* V      = (const float*)d_in[0];
    const float* graph  = (const float*)d_in[1];
    const float* lin0_w = (const float*)d_in[4];
    const float* lin0_b = (const float*)d_in[5];
    const float* att_w  = (const float*)d_in[6];
    const float* att_b  = (const float*)d_in[7];
    const float* agg    = (const float*)d_in[8];
    const float* pl     = (const float*)d_in[9];
    const float* cw     = (const float*)d_in[10];
    const float* cb     = (const float*)d_in[11];
    float* out = (float*)d_out;

    char* ws = (char*)d_ws;
    float* v_ws  = (float*)ws;                      // 3*65*256 f32 (199680 B)
    float* A_ws  = (float*)(ws + 200704);           // 9 f32
    u16*   Ebf2  = (u16*)(ws + 200768);             // 294912 B
    float* beff  = (float*)(ws + 495680);           // 128 f32
    u16*   X     = (u16*)(ws + 496192);             // 386*386*256 B = 38.1 MB

    k_prep_v<<<323, 256, 0, stream>>>(cw, cb, Ebf2, beff, V, lin0_w, lin0_b, v_ws);
    k_att<<<3, 256, 0, stream>>>(v_ws, att_w, att_b, agg, A_ws);
    k_pack<<<dim3(3, 386), 256, 0, stream>>>(graph, A_ws, X);
    k_conv9<<<1152, 256, 0, stream>>>(
        X, (const short*)Ebf2, beff, pl, graph, out);
}

// Round 10
// 141.556 us; speedup vs baseline: 1.2395x; 1.2395x over previous
//
#include <hip/hip_runtime.h>

typedef __attribute__((ext_vector_type(8))) short bf16x8;
typedef __attribute__((ext_vector_type(4))) float f32x4;
typedef unsigned int u32;
typedef unsigned short u16;
typedef unsigned long long u64;

#define S0 384
#define PLANE0 (384 * 384)
#define XR 386                     // packed image dim (386x386 records)
#define XROWB ((size_t)XR * 256)   // 98816 B per packed row

#define GLOAD_LDS(g, l) __builtin_amdgcn_global_load_lds( \
    (const __attribute__((address_space(1))) void*)(g),   \
    (__attribute__((address_space(3))) void*)(l), 16, 0, 0)

__device__ __forceinline__ u16 bfr(float f) {   // f32 -> bf16 RNE
    u32 b = __float_as_uint(f);
    b += 0x7fff + ((b >> 16) & 1);
    return (u16)(b >> 16);
}

// ---------------------------------------------------------------------------
// Fused: blocks 0..127 = weight-compose prep (E, beff); blocks 128..322 = v.
// ---------------------------------------------------------------------------
__global__ __launch_bounds__(256) void k_prep_v(
        const float* __restrict__ cw, const float* __restrict__ cb,
        u16* __restrict__ Ebf2, float* __restrict__ beff,
        const float* __restrict__ V,
        const float* __restrict__ lin0_w, const float* __restrict__ lin0_b,
        float* __restrict__ v_out) {
    const int tid = threadIdx.x;
    if (blockIdx.x < 128) {
        int o = blockIdx.x, i = tid & 127;
        __shared__ float4 Wo[128];
        __shared__ float red[128];
        Wo[i] = *(const float4*)(cw + (size_t)(o * 128 + i) * 4);
        __syncthreads();
        float a9[9];
#pragma unroll
        for (int q = 0; q < 9; ++q) a9[q] = 0.f;
        for (int m = 0; m < 128; ++m) {
            float4 w1 = *(const float4*)(cw + (size_t)(m * 128 + i) * 4);  // W[m][i]
            float4 w2 = Wo[m];                                             // W[o][m]
            a9[0] += w2.x * w1.x;
            a9[1] += w2.x * w1.y + w2.y * w1.x;
            a9[2] += w2.y * w1.y;
            a9[3] += w2.x * w1.z + w2.z * w1.x;
            a9[4] += w2.x * w1.w + w2.y * w1.z + w2.z * w1.y + w2.w * w1.x;
            a9[5] += w2.y * w1.w + w2.w * w1.y;
            a9[6] += w2.z * w1.z;
            a9[7] += w2.z * w1.w + w2.w * w1.z;
            a9[8] += w2.w * w1.w;
        }
        int icg = i >> 5, el = i & 31;
#pragma unroll
        for (int q = 0; q < 9; ++q)
            Ebf2[(size_t)((q * 4 + icg) * 128 + o) * 32 + el] = bfr(a9[q]);
        float4 wo = Wo[i];
        red[i] = cb[i] * (wo.x + wo.y + wo.z + wo.w);
        __syncthreads();
        for (int s = 64; s > 0; s >>= 1) {
            if (tid < 128 && i < s) red[i] += red[i + s];
            __syncthreads();
        }
        if (tid == 0) beff[o] = cb[o] + red[0];
    } else {
        int blk = blockIdx.x - 128;        // 0..194
        int k = blk / 65, m = blk % 65;
        int d = tid;
        int t = d >> 5, f = d & 31;
        const float* vbase = V + (size_t)t * 384 * 33 + f;
        float acc = lin0_b[m];
        for (int r = 0; r < 128; ++r) {
            float w = lin0_w[m * 130 + r];
            acc += w * vbase[(3 * r + k) * 33];
        }
        v_out[(size_t)blk * 256 + d] = acc;
    }
}

// ---------------------------------------------------------------------------
// Stage 2: attention scalars A[k,t] (9 floats).  float4-vectorized dots.
// ---------------------------------------------------------------------------
__global__ void k_att(const float* __restrict__ v,
                      const float* __restrict__ att_w,
                      const float* __restrict__ att_b,
                      const float* __restrict__ agg,
                      float* __restrict__ A_out) {
    int k = blockIdx.x;
    int tid = threadIdx.x;
    __shared__ __align__(16) float wv1[256], wv2[256];
    __shared__ float sbuf[3][65];
    __shared__ float Ck_s;
    __shared__ float sm[3];
    {
        int d = tid;
        float a1 = 0.f, a2 = 0.f;
#pragma unroll 8
        for (int h = 0; h < 64; ++h) {
            float w = att_w[((size_t)(k * 64 + h)) * 256 + d];
            a1 += agg[k * 128 + h] * w;
            a2 += agg[k * 128 + 64 + h] * w;
        }
        wv1[d] = a1;
        wv2[d] = a2;
    }
    if (tid == 0) {
        float c = 0.f;
        for (int h = 0; h < 64; ++h)
            c += (agg[k * 128 + h] + agg[k * 128 + 64 + h]) * att_b[k * 64 + h];
        Ck_s = c;
    }
    __syncthreads();
    if (tid < 195) {
        int t = tid / 65, m = tid % 65;
        const float4* vt = (const float4*)(v + ((size_t)(t * 65 + m)) * 256);
        const float4* vk = (const float4*)(v + ((size_t)(k * 65 + m)) * 256);
        const float4* w1 = (const float4*)wv1;
        const float4* w2 = (const float4*)wv2;
        float s = Ck_s;
#pragma unroll 8
        for (int d = 0; d < 64; ++d) {
            float4 a = vt[d], b = w1[d], c = vk[d], e = w2[d];
            s += a.x * b.x + a.y * b.y + a.z * b.z + a.w * b.w;
            s += c.x * e.x + c.y * e.y + c.z * e.z + c.w * e.w;
        }
        s = s > 0.f ? s : 0.01f * s;
        sbuf[t][m] = s;
    }
    __syncthreads();
    if (tid < 3) {
        float mx = sbuf[tid][0];
        for (int m = 1; m < 65; ++m) mx = fmaxf(mx, sbuf[tid][m]);
        sm[tid] = mx;
    }
    __syncthreads();
    if (tid == 0) {
        float mx = fmaxf(sm[0], fmaxf(sm[1], sm[2]));
        float e0 = __expf(sm[0] - mx), e1 = __expf(sm[1] - mx), e2 = __expf(sm[2] - mx);
        float inv = 1.f / (e0 + e1 + e2);
        A_out[k * 3 + 0] = e0 * inv;
        A_out[k * 3 + 1] = e1 * inv;
        A_out[k * 3 + 2] = e2 * inv;
    }
}

// ---------------------------------------------------------------------------
// Pack (coalesced transpose) + border zeroing fused.
// X record (y,x) = 256 B: two 128 B ic-halves; within half icH, slot s
// (16 B) holds ic-octet ((s ^ (x&7)) | icH<<3) of graph[.][y][x]*att9,
// zero outside 384x384.  (r4-proven conflict-free slot math.)
// grid (3, 386), 256 threads.
// ---------------------------------------------------------------------------
__global__ __launch_bounds__(256) void k_pack(
        const float* __restrict__ graph,
        const float* __restrict__ A9g,
        u16* __restrict__ X) {
    __shared__ u16 T[128 * 136];
    const int tid = threadIdx.x;
    const int xt = blockIdx.x, y = blockIdx.y;
    const int x0p = xt * 128;
    const uint4 z = {0u, 0u, 0u, 0u};

    if (y >= 384) {   // rows 384,385: all-zero
        int nunits = (xt == 2) ? 130 * 16 : 128 * 16;
        for (int u = tid; u < nunits; u += 256) {
            int x = x0p + (u >> 4), j = u & 15;
            *(uint4*)((char*)X + ((size_t)y * XR + x) * 256 + j * 16) = z;
        }
        return;
    }

    // phase A: read 4 ic x 16 x, transpose into LDS
    const int ic0 = (tid & 31) * 4;
    const int xc = tid >> 5;                 // 0..7
    float ar[3];
    ar[0] = A9g[(y % 3) * 3 + 0];
    ar[1] = A9g[(y % 3) * 3 + 1];
    ar[2] = A9g[(y % 3) * 3 + 2];
    const int m0 = (x0p + xc * 16) % 3;
    float facs[3];
    facs[0] = ar[m0];
    facs[1] = ar[m0 + 1 == 3 ? 0 : m0 + 1];
    facs[2] = ar[m0 + 2 >= 3 ? m0 - 1 : m0 + 2];

    float vals[4][16];
#pragma unroll
    for (int ici = 0; ici < 4; ++ici) {
        const float* g = graph + (size_t)(ic0 + ici) * PLANE0 + (size_t)y * S0 + x0p + xc * 16;
#pragma unroll
        for (int q = 0; q < 4; ++q) {
            float4 f = *(const float4*)(g + q * 4);
            vals[ici][q * 4 + 0] = f.x;
            vals[ici][q * 4 + 1] = f.y;
            vals[ici][q * 4 + 2] = f.z;
            vals[ici][q * 4 + 3] = f.w;
        }
    }
#pragma unroll
    for (int e = 0; e < 16; ++e) {
        float f = facs[e % 3];
        int x = xc * 16 + e;
        u16 q0 = bfr(vals[0][e] * f);
        u16 q1 = bfr(vals[1][e] * f);
        u16 q2 = bfr(vals[2][e] * f);
        u16 q3 = bfr(vals[3][e] * f);
        u64 w = (u64)q0 | ((u64)q1 << 16) | ((u64)q2 << 32) | ((u64)q3 << 48);
        *(u64*)(T + x * 136 + ic0) = w;
    }
    __syncthreads();

    // phase B: apply slot swizzle, write coalesced 16B units
#pragma unroll
    for (int i = 0; i < 8; ++i) {
        int u = tid + 256 * i;               // 0..2047
        int x = u >> 4, j = u & 15;
        int oct = (j & 8) | ((j & 7) ^ (x & 7));
        uint4 w = *(const uint4*)(T + x * 136 + oct * 8);
        *(uint4*)((char*)X + ((size_t)y * XR + x0p + x) * 256 + j * 16) = w;
    }
    // cols 384,385 zero (only xt==2 borders them)
    if (xt == 2 && tid < 32) {
        int x = 384 + (tid >> 4), j = tid & 15;
        *(uint4*)((char*)X + ((size_t)y * XR + x) * 256 + j * 16) = z;
    }
}

// ---------------------------------------------------------------------------
// Fused 3x3 conv (composed 2x2∘2x2), GEMM M=128oc K=1152 N=147456px.
// Block: 128oc x 48px x 2rows; wave = 64oc (mh) x 48px x 1row (rh).
// LDS: 4 rows x 52 px x 256 B = 53248 B -> 3 blocks/CU (3 waves/SIMD).
// Stage once via global_load_lds (13 x 16B per thread, uniform), 1 barrier,
// 36 barrier-free k-steps; A regs depth-4 pipeline, B ds_reads depth-2.
// LDS read: byte = row*13312 + px*256 + icH*128 + ((h&7)^(px&7))*16.
// Epilogue: out = relu(pl*(acc+beff)+graph).
// grid 1536 = 8 XCD x 192 (chunked swizzle), 256 threads.
// ---------------------------------------------------------------------------
__global__ __launch_bounds__(256, 3) void k_conv9(
        const u16* __restrict__ X,
        const short* __restrict__ Ebf2,
        const float* __restrict__ beff,
        const float* __restrict__ pl,
        const float* __restrict__ graph,
        float* __restrict__ out) {
    __shared__ __align__(16) char Bt[53248];    // 4 rows x 52 px x 256 B
    const int tid = threadIdx.x;
    const int lane = tid & 63, wave = tid >> 6;
    const int l15 = lane & 15, l16 = lane >> 4;

    const int phys = blockIdx.x;                // 0..1535 = 8 x 192
    const int logical = (phys & 7) * 192 + (phys >> 3);
    const int bx = logical & 7, by = logical >> 3;
    const int x0 = bx * 48, y0 = by * 2;
    const int mh = wave & 1, rh = wave >> 1;
    const int ocbase = mh * 64;

    // ---- stage 4 packed rows (13312 B each = 832 units), 13 units/thread ----
    {
        const char* gsrc = (const char*)X + ((size_t)y0 * XR + x0) * 256;
#pragma unroll
        for (int i = 0; i < 13; ++i) {
            int u = tid + i * 256;               // 0..3327
            int r = u / 832;
            int off = (u - r * 832) * 16;
            GLOAD_LDS(gsrc + (size_t)r * XROWB + off, Bt + u * 16);
        }
    }

    // ---- A-register pipeline, depth 4 ----
#define ALOAD(dst, s) {                                                        \
        const short* Ap = Ebf2 + ((size_t)((s) * 128 + ocbase + l15) << 5)     \
                          + l16 * 8;                                           \
        dst[0] = *(const bf16x8*)(Ap);                                         \
        dst[1] = *(const bf16x8*)(Ap + 512);                                   \
        dst[2] = *(const bf16x8*)(Ap + 1024);                                  \
        dst[3] = *(const bf16x8*)(Ap + 1536); }

    bf16x8 ap[4][4];
    ALOAD(ap[0], 0); ALOAD(ap[1], 1); ALOAD(ap[2], 2); ALOAD(ap[3], 3);

    __syncthreads();

    f32x4 acc[4][3];    // [m][n]
#pragma unroll
    for (int a = 0; a < 4; ++a)
#pragma unroll
        for (int b = 0; b < 3; ++b)
            acc[a][b] = (f32x4){0.f, 0.f, 0.f, 0.f};

    // B LDS byte address for k-step s, N-frag n (s,n compile-time)
#define BADDR(s, n) (Bt + (rh + ((s) >> 2) / 3) * 13312                        \
        + ((l15 + (n) * 16 + ((s) >> 2) % 3) << 8)                             \
        + (((((s) & 3) * 4 + l16) >> 3) << 7)                                  \
        + ((((((s) & 3) * 4 + l16) & 7) ^ ((l15 + (n) * 16 + ((s) >> 2) % 3) & 7)) << 4))

    bf16x8 bp[2][3];
#pragma unroll
    for (int n = 0; n < 3; ++n) bp[0][n] = *(const bf16x8*)BADDR(0, n);

#pragma unroll
    for (int s = 0; s < 36; ++s) {
        const int cur = s & 1;
        if (s < 35) {
#pragma unroll
            for (int n = 0; n < 3; ++n)
                bp[cur ^ 1][n] = *(const bf16x8*)BADDR(s + 1, n);
        }
        __builtin_amdgcn_s_setprio(1);
#pragma unroll
        for (int n = 0; n < 3; ++n) {
            acc[0][n] = __builtin_amdgcn_mfma_f32_16x16x32_bf16(ap[s & 3][0], bp[cur][n], acc[0][n], 0, 0, 0);
            acc[1][n] = __builtin_amdgcn_mfma_f32_16x16x32_bf16(ap[s & 3][1], bp[cur][n], acc[1][n], 0, 0, 0);
            acc[2][n] = __builtin_amdgcn_mfma_f32_16x16x32_bf16(ap[s & 3][2], bp[cur][n], acc[2][n], 0, 0, 0);
            acc[3][n] = __builtin_amdgcn_mfma_f32_16x16x32_bf16(ap[s & 3][3], bp[cur][n], acc[3][n], 0, 0, 0);
        }
        __builtin_amdgcn_s_setprio(0);
        if (s + 4 < 36) ALOAD(ap[s & 3], s + 4);
    }
#undef ALOAD
#undef BADDR

    // ---- epilogue: out = relu(pl*(acc + beff) + graph) ----
    const float plv = pl[0];
    const int yy = y0 + rh;
#pragma unroll
    for (int m = 0; m < 4; ++m) {
#pragma unroll
        for (int r4 = 0; r4 < 4; ++r4) {
            const int oc = ocbase + m * 16 + l16 * 4 + r4;
            const float bias = beff[oc];
            const float* grow = graph + (size_t)oc * PLANE0 + (size_t)yy * S0 + x0;
            float* orow = out + (size_t)oc * PLANE0 + (size_t)yy * S0 + x0;
#pragma unroll
            for (int n = 0; n < 3; ++n) {
                const int xx = n * 16 + l15;
                float v = plv * (acc[m][n][r4] + bias) + grow[xx];
                orow[xx] = v > 0.f ? v : 0.f;
            }
        }
    }
}

// ---------------------------------------------------------------------------
extern "C" void kernel_launch(void* const* d_in, const int* in_sizes, int n_in,
                              void* d_out, int out_size, void* d_ws, size_t ws_size,
                              hipStream_t stream) {
    (void)in_sizes; (void)n_in; (void)out_size; (void)ws_size;
    const float* V      = (const float*)d_in[0];
    const float* graph  = (const float*)d_in[1];
    const float* lin0_w = (const float*)d_in[4];
    const float* lin0_b = (const float*)d_in[5];
    const float* att_w  = (const float*)d_in[6];
    const float* att_b  = (const float*)d_in[7];
    const float* agg    = (const float*)d_in[8];
    const float* pl     = (const float*)d_in[9];
    const float* cw     = (const float*)d_in[10];
    const float* cb     = (const float*)d_in[11];
    float* out = (float*)d_out;

    char* ws = (char*)d_ws;
    float* v_ws  = (float*)ws;                      // 3*65*256 f32 (199680 B)
    float* A_ws  = (float*)(ws + 200704);           // 9 f32
    u16*   Ebf2  = (u16*)(ws + 200768);             // 294912 B
    float* beff  = (float*)(ws + 495680);           // 128 f32
    u16*   X     = (u16*)(ws + 496192);             // 386*386*256 B = 38.1 MB

    k_prep_v<<<323, 256, 0, stream>>>(cw, cb, Ebf2, beff, V, lin0_w, lin0_b, v_ws);
    k_att<<<3, 256, 0, stream>>>(v_ws, att_w, att_b, agg, A_ws);
    k_pack<<<dim3(3, 386), 256, 0, stream>>>(graph, A_ws, X);
    k_conv9<<<1536, 256, 0, stream>>>(
        X, (const short*)Ebf2, beff, pl, graph, out);
}